// Round 1
// baseline (588.994 us; speedup 1.0000x reference)
//
#include <hip/hip_runtime.h>
#include <cstdint>
#include <cstddef>

// Problem dims (fixed)
#define NN 131072      // nodes
#define EE 262144      // events
// msg GEMM: K = 448 = [mem_s 128 | mem_d 128 | raw 128 | tenc_s 32 | tenc_d 32], Nout = 256
// gru GEMM: K = 256 = [aggr 128 | memory 128], Nout = 512 = [r | z | i_n | h_n]

typedef __attribute__((ext_vector_type(8))) short bf16x8;
typedef __attribute__((ext_vector_type(4))) float f32x4;

__device__ __forceinline__ unsigned short f2bf(float f) {
    unsigned int u = __builtin_bit_cast(unsigned int, f);
    u += 0x7FFFu + ((u >> 16) & 1u);   // RNE
    return (unsigned short)(u >> 16);
}
__device__ __forceinline__ float bf2f(unsigned short s) {
    unsigned int u = ((unsigned int)s) << 16;
    return __builtin_bit_cast(float, u);
}
__device__ __forceinline__ float sigmoidf_(float x) { return 1.0f / (1.0f + __expf(-x)); }
__device__ __forceinline__ float tanhf_(float x) {
    float ax = fabsf(x);
    float e = __expf(-2.0f * ax);
    return copysignf((1.0f - e) / (1.0f + e), x);
}
__device__ __forceinline__ bf16x8 pack8(const float* f) {
    bf16x8 o;
#pragma unroll
    for (int i = 0; i < 8; ++i) o[i] = (short)f2bf(f[i]);
    return o;
}

// logical W' for the fused message GEMM (256 out x 448 in)
__device__ __forceinline__ float wmsg_val(int n, int k, const float* Ws, const float* Wd) {
    if (n < 128) {
        return (k < 416) ? Ws[n * 416 + k] : 0.0f;           // [mem_s, mem_d, raw, tenc_s]
    } else {
        int m = n - 128;
        if (k < 128)       return Wd[m * 416 + 128 + k];     // X' mem_s <- Wd block 1
        else if (k < 256)  return Wd[m * 416 + (k - 128)];   // X' mem_d <- Wd block 0
        else if (k < 384)  return Wd[m * 416 + k];           // raw
        else if (k < 416)  return 0.0f;                      // tenc_s unused by msg_d
        else               return Wd[m * 416 + 384 + (k - 416)]; // tenc_d
    }
}
// logical W for the GRU GEMM (512 out x 256 in)
__device__ __forceinline__ float wgru_val(int j, int k, const float* Wih, const float* Whh) {
    if (j < 256)      return (k < 128) ? Wih[j * 128 + k] : Whh[j * 128 + (k - 128)];
    else if (j < 384) return (k < 128) ? Wih[j * 128 + k] : 0.0f;
    else              return (k < 128) ? 0.0f : Whh[(j - 128) * 128 + (k - 128)];
}

// ---------------- prep: message weight in MFMA fragment order ----------------
// Wmf[((c*16 + nt)*64 + lane)*8 + j] ; c 0..13, nt 0..15
__global__ void k_prep_msgfrag(const float* __restrict__ Ws, const float* __restrict__ Wd,
                               const float* __restrict__ bs, const float* __restrict__ bd,
                               unsigned short* __restrict__ Wmf, float* __restrict__ bm) {
    int b = blockIdx.x;              // c*16 + nt
    int c = b >> 4, nt = b & 15;
    int lane = threadIdx.x;
    int col0 = lane & 15, q = lane >> 4;
    int n = nt * 16 + col0;
    float f[8];
#pragma unroll
    for (int j = 0; j < 8; ++j) f[j] = wmsg_val(n, c * 32 + q * 8 + j, Ws, Wd);
    ((bf16x8*)Wmf)[(size_t)b * 64 + lane] = pack8(f);
    if (b == 0)
        for (int i = lane; i < 256; i += 64) bm[i] = (i < 128) ? bs[i] : bd[i - 128];
}

// ---------------- prep: GRU weight in MFMA fragment order ----------------
// Wgf[((c*32 + nt)*64 + lane)*8 + j] ; c 0..7, nt 0..31
__global__ void k_prep_grufrag(const float* __restrict__ Wih, const float* __restrict__ Whh,
                               const float* __restrict__ bih, const float* __restrict__ bhh,
                               unsigned short* __restrict__ Wgf, float* __restrict__ bg) {
    int b = blockIdx.x;              // c*32 + nt
    int c = b >> 5, nt = b & 31;
    int lane = threadIdx.x;
    int col0 = lane & 15, q = lane >> 4;
    int j0 = nt * 16 + col0;
    float f[8];
#pragma unroll
    for (int j = 0; j < 8; ++j) f[j] = wgru_val(j0, c * 32 + q * 8 + j, Wih, Whh);
    ((bf16x8*)Wgf)[(size_t)b * 64 + lane] = pack8(f);
    if (b == 0)
        for (int i = lane; i < 512; i += 64)
            bg[i] = (i < 256) ? (bih[i] + bhh[i]) : ((i < 384) ? bih[i] : bhh[i - 128]);
}

// ---------------- memory fp32 -> bf16 table ----------------
__global__ void k_memconv(const float* __restrict__ in, unsigned short* __restrict__ outp) {
    int gid = blockIdx.x * 256 + threadIdx.x;
    const float4 v = ((const float4*)in)[gid];
    ushort4 o;
    o.x = f2bf(v.x); o.y = f2bf(v.y); o.z = f2bf(v.z); o.w = f2bf(v.w);
    *(ushort4*)(outp + (size_t)gid * 4) = o;
}

// ---------------- per-event: t_rel, counts, timestamp max ----------------
__global__ void k_pre(const int* __restrict__ t, const int* __restrict__ src,
                      const int* __restrict__ dst, const int* __restrict__ lu,
                      float* __restrict__ trel_s, float* __restrict__ trel_d,
                      int* cnt, int* lu_tmp) {
    int e = blockIdx.x * 256 + threadIdx.x;
    int s = src[e], d = dst[e], tv = t[e];
    trel_s[e] = (float)(tv - lu[s]);
    trel_d[e] = (float)(tv - lu[d]);
    atomicAdd(&cnt[s], 1);
    atomicAdd(&cnt[d], 1);
    atomicMax(&lu_tmp[s], tv);
    atomicMax(&lu_tmp[d], tv);
}

// ---------------- CSR scan: 3 stages ----------------
__global__ void k_scan1(const int* __restrict__ cnt, int* __restrict__ bsum) {
    __shared__ int red[256];
    int tid = threadIdx.x;
    red[tid] = cnt[blockIdx.x * 256 + tid];
    __syncthreads();
    for (int s = 128; s > 0; s >>= 1) {
        if (tid < s) red[tid] += red[tid + s];
        __syncthreads();
    }
    if (tid == 0) bsum[blockIdx.x] = red[0];
}
__global__ void k_scan2(const int* __restrict__ bsum, int* __restrict__ boff) {
    __shared__ int sb[512];
    int tid = threadIdx.x;
    int v = bsum[tid];
    sb[tid] = v;
    __syncthreads();
    for (int d = 1; d < 512; d <<= 1) {
        int u = (tid >= d) ? sb[tid - d] : 0;
        __syncthreads();
        sb[tid] += u;
        __syncthreads();
    }
    boff[tid] = sb[tid] - v;   // exclusive
}
__global__ void k_scan3(const int* __restrict__ cnt, const int* __restrict__ boff,
                        int* __restrict__ off, int* __restrict__ cursor) {
    __shared__ int sb[256];
    int tid = threadIdx.x;
    int i = blockIdx.x * 256 + tid;
    int v = cnt[i];
    sb[tid] = v;
    __syncthreads();
    for (int d = 1; d < 256; d <<= 1) {
        int u = (tid >= d) ? sb[tid - d] : 0;
        __syncthreads();
        sb[tid] += u;
        __syncthreads();
    }
    int o = boff[blockIdx.x] + sb[tid] - v;
    off[i] = o;
    cursor[i] = o;
}
// inverse permutation: event-side -> sorted position
__global__ void k_fill(const int* __restrict__ src, const int* __restrict__ dst,
                       int* cursor, int* __restrict__ pos2) {
    int e2 = blockIdx.x * 256 + threadIdx.x;   // [0,2E): <E = s-side, >=E = d-side
    int node = (e2 < EE) ? src[e2] : dst[e2 - EE];
    pos2[e2] = atomicAdd(&cursor[node], 1);
}

// ---------------- message GEMM -> msg_sorted[2E][128] bf16 ----------------
// 64 events x 256 outputs, K=448 in 14 chunks. acc[4][4] (64 acc regs) so the
// unified-RF wave footprint fits 3 blocks/CU (was 128 acc regs -> 2 blocks/CU,
// Occupancy 20%). B frags direct from global; A double-buffered in LDS.
// Epilogue: per-wave LDS transpose (reusing As) -> 16B coalesced row stores.
__launch_bounds__(256, 3)
__global__ void k_msg(const unsigned short* __restrict__ memb,
                      const float* __restrict__ raw,
                      const float* __restrict__ trel_s,
                      const float* __restrict__ trel_d,
                      const unsigned short* __restrict__ Wmf,
                      const float* __restrict__ bm,
                      const int* __restrict__ src, const int* __restrict__ dst,
                      const int* __restrict__ pos2,
                      const float* __restrict__ tw, const float* __restrict__ tb,
                      unsigned short* __restrict__ msg) {
    __shared__ int s_idx[64], d_idx[64], s_pos[64], d_pos[64];
    __shared__ float s_tw[32], s_tb[32];
    __shared__ __align__(16) unsigned short As[2][64 * 40];

    const int tid = threadIdx.x;
    const int e0 = blockIdx.x * 64;
    if (tid < 64)        { s_idx[tid] = src[e0 + tid];            s_pos[tid] = pos2[e0 + tid]; }
    else if (tid < 128)  { d_idx[tid - 64] = dst[e0 + tid - 64];  d_pos[tid - 64] = pos2[EE + e0 + tid - 64]; }
    else if (tid < 160)  s_tw[tid - 128] = tw[tid - 128];
    else if (tid < 192)  s_tb[tid - 160] = tb[tid - 160];
    __syncthreads();

    const int lane = tid & 63, w = tid >> 6;
    const int col0 = lane & 15, q = lane >> 4;

    auto stage = [&](int cc) {
        unsigned short* A = As[cc & 1];
        if (cc < 8) {
            // 64 rows x 32 cols bf16 from memory table: 1 x 16B per thread
            int row = tid >> 2, seg = tid & 3;
            int node = (cc < 4) ? s_idx[row] : d_idx[row];
            bf16x8 v = *(const bf16x8*)(memb + (size_t)node * 128 + (cc & 3) * 32 + seg * 8);
            *(bf16x8*)&A[row * 40 + seg * 8] = v;
        } else if (cc < 12) {
            // 64 rows x 32 cols fp32 raw: 2 x float4 per thread
#pragma unroll
            for (int i = 0; i < 2; ++i) {
                int lin = tid + 256 * i;
                int row = lin >> 3, seg = lin & 7;
                const float4 v = *(const float4*)(raw + (size_t)(e0 + row) * 128 + (cc - 8) * 32 + seg * 4);
                ushort4 o;
                o.x = f2bf(v.x); o.y = f2bf(v.y); o.z = f2bf(v.z); o.w = f2bf(v.w);
                *(ushort4*)&A[row * 40 + seg * 4] = o;
            }
        } else {
            // time encoding: 64 rows x 32 cols, 8 cos per thread
            int row = tid >> 2, quarter = tid & 3;
            float tr = (cc == 12) ? trel_s[e0 + row] : trel_d[e0 + row];
            float f[8];
#pragma unroll
            for (int j2 = 0; j2 < 8; ++j2) {
                int jj = quarter * 8 + j2;
                f[j2] = __cosf(tr * s_tw[jj] + s_tb[jj]);
            }
            *(bf16x8*)&A[row * 40 + quarter * 8] = pack8(f);
        }
    };

    f32x4 acc[4][4];
#pragma unroll
    for (int a = 0; a < 4; ++a)
#pragma unroll
        for (int b = 0; b < 4; ++b)
#pragma unroll
            for (int i = 0; i < 4; ++i) acc[a][b][i] = 0.0f;

    stage(0);
    __syncthreads();

    for (int c = 0; c < 14; ++c) {
        bf16x8 bfr[4];
        const bf16x8* Wc = (const bf16x8*)Wmf + (size_t)c * 16 * 64;
#pragma unroll
        for (int nl = 0; nl < 4; ++nl)
            bfr[nl] = Wc[(w * 4 + nl) * 64 + lane];
        const unsigned short* A = As[c & 1];
        bf16x8 afr[4];
#pragma unroll
        for (int mt = 0; mt < 4; ++mt)
            afr[mt] = *(const bf16x8*)&A[(mt * 16 + col0) * 40 + q * 8];
        if (c < 13) stage(c + 1);
#pragma unroll
        for (int mt = 0; mt < 4; ++mt)
#pragma unroll
            for (int nl = 0; nl < 4; ++nl)
                acc[mt][nl] = __builtin_amdgcn_mfma_f32_16x16x32_bf16(afr[mt], bfr[nl], acc[mt][nl], 0, 0, 0);
        __syncthreads();
    }

    // ---- epilogue: bias+relu, per-wave LDS transpose (reuse As), 16B stores ----
    // per-wave scratch: 16 rows x 80 shorts (160B stride, 16B aligned); row holds
    // 8 granules of 16B, granule-XOR-swizzled by row to break bank aliasing.
    unsigned short* scr = &As[0][0] + w * 1280;
    const bool is_s = (w < 2);
#pragma unroll
    for (int mt = 0; mt < 4; ++mt) {
#pragma unroll
        for (int nl = 0; nl < 4; ++nl) {
            int j = (w * 4 + nl) * 16 + col0;
            float bv = bm[j];
            int gl = nl * 2 + (col0 >> 3);      // logical 16B granule within 64-col tile
            int ci = col0 & 7;                  // short index within granule
#pragma unroll
            for (int r = 0; r < 4; ++r) {
                int rr = q * 4 + r;             // row within 16-row tile
                float v = fmaxf(acc[mt][nl][r] + bv, 0.0f);
                scr[rr * 80 + ((gl + rr) & 7) * 8 + ci] = f2bf(v);
            }
        }
        // wave-local: DS ops are in-order per wave; just wait for writes to land
        asm volatile("s_waitcnt lgkmcnt(0)" ::: "memory");
        {
            int rr2 = lane & 15, p = lane >> 4;
            int ev = mt * 16 + rr2;
            int pos = is_s ? s_pos[ev] : d_pos[ev];
            bf16x8 v0 = *(const bf16x8*)&scr[rr2 * 80 + (((2 * p)     + rr2) & 7) * 8];
            bf16x8 v1 = *(const bf16x8*)&scr[rr2 * 80 + (((2 * p + 1) + rr2) & 7) * 8];
            unsigned short* dstp = msg + (size_t)pos * 128 + (w & 1) * 64 + p * 16;
            *(bf16x8*)dstp = v0;
            *(bf16x8*)(dstp + 8) = v1;
        }
        asm volatile("s_waitcnt lgkmcnt(0)" ::: "memory");
    }
}

// ---------------- fused mean-aggregation (sorted, contiguous) + GRU ----------------
// 32 nodes/block, 256 threads. B frags direct from global; no barriers in K-loop.
__launch_bounds__(256, 3)
__global__ void k_gru(const unsigned short* __restrict__ msg,
                      const int* __restrict__ off, const int* __restrict__ cnt,
                      const float* __restrict__ memory,
                      const unsigned short* __restrict__ Wgf,
                      const float* __restrict__ bg,
                      float* __restrict__ out) {
    __shared__ __align__(16) unsigned short Xs[32 * 264];

    const int tid = threadIdx.x;
    const int n0 = blockIdx.x * 32;

    // aggregation: 8 threads/node, 16 feats each; msg rows contiguous per node
    {
        int g = tid >> 3, sub = tid & 7;
        int node = n0 + g;
        int beg = off[node], cn = cnt[node];
        float a[16];
#pragma unroll
        for (int i = 0; i < 16; ++i) a[i] = 0.0f;
        for (int m = 0; m < cn; ++m) {
            const bf16x8* p = (const bf16x8*)(msg + (size_t)(beg + m) * 128 + sub * 16);
            bf16x8 v0 = p[0], v1 = p[1];
#pragma unroll
            for (int k = 0; k < 8; ++k) {
                a[k]     += bf2f((unsigned short)v0[k]);
                a[8 + k] += bf2f((unsigned short)v1[k]);
            }
        }
        float inv = 1.0f / (float)(cn > 1 ? cn : 1);
#pragma unroll
        for (int i = 0; i < 16; ++i) a[i] *= inv;
        *(bf16x8*)&Xs[g * 264 + sub * 16] = pack8(&a[0]);
        *(bf16x8*)&Xs[g * 264 + sub * 16 + 8] = pack8(&a[8]);
        // memory half
        float f[16];
        const float4* mp = (const float4*)(memory + (size_t)node * 128 + sub * 16);
#pragma unroll
        for (int s = 0; s < 4; ++s) {
            float4 v = mp[s];
            f[s * 4 + 0] = v.x; f[s * 4 + 1] = v.y; f[s * 4 + 2] = v.z; f[s * 4 + 3] = v.w;
        }
        *(bf16x8*)&Xs[g * 264 + 128 + sub * 16] = pack8(&f[0]);
        *(bf16x8*)&Xs[g * 264 + 128 + sub * 16 + 8] = pack8(&f[8]);
    }
    __syncthreads();

    const int lane = tid & 63, w = tid >> 6;
    const int col0 = lane & 15, q = lane >> 4;

    f32x4 acc[2][4][2];   // [mt][gate][fh]
#pragma unroll
    for (int a = 0; a < 2; ++a)
#pragma unroll
        for (int g = 0; g < 4; ++g)
#pragma unroll
            for (int f = 0; f < 2; ++f)
#pragma unroll
                for (int i = 0; i < 4; ++i) acc[a][g][f][i] = 0.0f;

#pragma unroll
    for (int c = 0; c < 8; ++c) {
        bf16x8 bfr[4][2];
        const bf16x8* Wc = (const bf16x8*)Wgf + (size_t)c * 32 * 64;
#pragma unroll
        for (int g = 0; g < 4; ++g)
#pragma unroll
            for (int fh = 0; fh < 2; ++fh)
                bfr[g][fh] = Wc[(8 * g + 2 * w + fh) * 64 + lane];
        bf16x8 afr[2];
#pragma unroll
        for (int mt = 0; mt < 2; ++mt)
            afr[mt] = *(const bf16x8*)&Xs[(mt * 16 + col0) * 264 + c * 32 + q * 8];
#pragma unroll
        for (int mt = 0; mt < 2; ++mt)
#pragma unroll
            for (int g = 0; g < 4; ++g)
#pragma unroll
                for (int fh = 0; fh < 2; ++fh)
                    acc[mt][g][fh] = __builtin_amdgcn_mfma_f32_16x16x32_bf16(afr[mt], bfr[g][fh], acc[mt][g][fh], 0, 0, 0);
    }

    // epilogue: gates + blend
#pragma unroll
    for (int fh = 0; fh < 2; ++fh) {
        int feat = w * 32 + fh * 16 + col0;
        float b_r = bg[feat], b_z = bg[128 + feat], b_in = bg[256 + feat], b_hn = bg[384 + feat];
#pragma unroll
        for (int mt = 0; mt < 2; ++mt) {
#pragma unroll
            for (int r = 0; r < 4; ++r) {
                int node = n0 + mt * 16 + q * 4 + r;
                float rr = sigmoidf_(acc[mt][0][fh][r] + b_r);
                float zz = sigmoidf_(acc[mt][1][fh][r] + b_z);
                float nn = tanhf_((acc[mt][2][fh][r] + b_in) + rr * (acc[mt][3][fh][r] + b_hn));
                float h = memory[(size_t)node * 128 + feat];
                out[(size_t)node * 128 + feat] = (1.0f - zz) * nn + zz * h;
            }
        }
    }
}

// ---------------- last_update -> float output ----------------
__global__ void k_lu(const int* __restrict__ lu_tmp, float* __restrict__ outp) {
    int i = blockIdx.x * 256 + threadIdx.x;
    outp[i] = (float)lu_tmp[i];
}

extern "C" void kernel_launch(void* const* d_in, const int* in_sizes, int n_in,
                              void* d_out, int out_size, void* d_ws, size_t ws_size,
                              hipStream_t stream) {
    const float* memory = (const float*)d_in[0];
    const float* raw    = (const float*)d_in[1];
    const float* tw     = (const float*)d_in[2];
    const float* tb     = (const float*)d_in[3];
    const float* Wms    = (const float*)d_in[4];
    const float* bms    = (const float*)d_in[5];
    const float* Wmd    = (const float*)d_in[6];
    const float* bmd    = (const float*)d_in[7];
    const float* Wih    = (const float*)d_in[8];
    const float* Whh    = (const float*)d_in[9];
    const float* bih    = (const float*)d_in[10];
    const float* bhh    = (const float*)d_in[11];
    const int* src = (const int*)d_in[12];
    const int* dst = (const int*)d_in[13];
    const int* t   = (const int*)d_in[14];
    const int* lu  = (const int*)d_in[15];

    char* ws = (char*)d_ws;
    size_t ob = 0;
    unsigned short* memb = (unsigned short*)(ws + ob); ob += (size_t)NN * 128 * 2;       // 32 MB
    unsigned short* msg  = (unsigned short*)(ws + ob); ob += (size_t)2 * EE * 128 * 2;   // 128 MB (sorted)
    float* trel_s        = (float*)(ws + ob);          ob += (size_t)EE * 4;
    float* trel_d        = (float*)(ws + ob);          ob += (size_t)EE * 4;
    int* cnt             = (int*)(ws + ob);            ob += (size_t)NN * 4;
    int* off             = (int*)(ws + ob);            ob += (size_t)NN * 4;
    int* cursor          = (int*)(ws + ob);            ob += (size_t)NN * 4;
    int* lu_tmp          = (int*)(ws + ob);            ob += (size_t)NN * 4;
    int* pos2            = (int*)(ws + ob);            ob += (size_t)2 * EE * 4;         // 2 MB
    int* bsum            = (int*)(ws + ob);            ob += 512 * 4;
    int* boff            = (int*)(ws + ob);            ob += 512 * 4;
    unsigned short* Wmf  = (unsigned short*)(ws + ob); ob += (size_t)14 * 16 * 64 * 8 * 2;
    float* bm            = (float*)(ws + ob);          ob += 256 * 4;
    unsigned short* Wgf  = (unsigned short*)(ws + ob); ob += (size_t)8 * 32 * 64 * 8 * 2;
    float* bg            = (float*)(ws + ob);          ob += 512 * 4;

    float* out = (float*)d_out;

    hipMemsetAsync(cnt, 0, (size_t)NN * 4, stream);
    hipMemsetAsync(lu_tmp, 0, (size_t)NN * 4, stream);

    k_prep_msgfrag<<<14 * 16, 64, 0, stream>>>(Wms, Wmd, bms, bmd, Wmf, bm);
    k_prep_grufrag<<<8 * 32, 64, 0, stream>>>(Wih, Whh, bih, bhh, Wgf, bg);
    k_memconv<<<(NN * 128 / 4) / 256, 256, 0, stream>>>(memory, memb);
    k_pre<<<EE / 256, 256, 0, stream>>>(t, src, dst, lu, trel_s, trel_d, cnt, lu_tmp);
    k_scan1<<<512, 256, 0, stream>>>(cnt, bsum);
    k_scan2<<<1, 512, 0, stream>>>(bsum, boff);
    k_scan3<<<512, 256, 0, stream>>>(cnt, boff, off, cursor);
    k_fill<<<2 * EE / 256, 256, 0, stream>>>(src, dst, cursor, pos2);
    k_msg<<<EE / 64, 256, 0, stream>>>(memb, raw, trel_s, trel_d, Wmf, bm, src, dst, pos2, tw, tb, msg);
    k_gru<<<NN / 32, 256, 0, stream>>>(msg, off, cnt, memory, Wgf, bg, out);
    k_lu<<<NN / 256, 256, 0, stream>>>(lu_tmp, out + (size_t)NN * 128);
}

// Round 2
// 566.596 us; speedup vs baseline: 1.0395x; 1.0395x over previous
//
#include <hip/hip_runtime.h>
#include <cstdint>
#include <cstddef>

// Problem dims (fixed)
#define NN 131072      // nodes
#define EE 262144      // events
// msg GEMM: K = 448 = [mem_s 128 | mem_d 128 | raw 128 | tenc_s 32 | tenc_d 32], Nout = 256
// gru GEMM: K = 256 = [aggr 128 | memory 128], Nout = 512 = [r | z | i_n | h_n]

typedef __attribute__((ext_vector_type(8))) short bf16x8;
typedef __attribute__((ext_vector_type(4))) float f32x4;

__device__ __forceinline__ unsigned short f2bf(float f) {
    unsigned int u = __builtin_bit_cast(unsigned int, f);
    u += 0x7FFFu + ((u >> 16) & 1u);   // RNE
    return (unsigned short)(u >> 16);
}
__device__ __forceinline__ float bf2f(unsigned short s) {
    unsigned int u = ((unsigned int)s) << 16;
    return __builtin_bit_cast(float, u);
}
__device__ __forceinline__ float sigmoidf_(float x) { return 1.0f / (1.0f + __expf(-x)); }
__device__ __forceinline__ float tanhf_(float x) {
    float ax = fabsf(x);
    float e = __expf(-2.0f * ax);
    return copysignf((1.0f - e) / (1.0f + e), x);
}
__device__ __forceinline__ bf16x8 pack8(const float* f) {
    bf16x8 o;
#pragma unroll
    for (int i = 0; i < 8; ++i) o[i] = (short)f2bf(f[i]);
    return o;
}

// logical W' for the fused message GEMM (256 out x 448 in)
__device__ __forceinline__ float wmsg_val(int n, int k, const float* Ws, const float* Wd) {
    if (n < 128) {
        return (k < 416) ? Ws[n * 416 + k] : 0.0f;           // [mem_s, mem_d, raw, tenc_s]
    } else {
        int m = n - 128;
        if (k < 128)       return Wd[m * 416 + 128 + k];     // X' mem_s <- Wd block 1
        else if (k < 256)  return Wd[m * 416 + (k - 128)];   // X' mem_d <- Wd block 0
        else if (k < 384)  return Wd[m * 416 + k];           // raw
        else if (k < 416)  return 0.0f;                      // tenc_s unused by msg_d
        else               return Wd[m * 416 + 384 + (k - 416)]; // tenc_d
    }
}
// logical W for the GRU GEMM (512 out x 256 in)
__device__ __forceinline__ float wgru_val(int j, int k, const float* Wih, const float* Whh) {
    if (j < 256)      return (k < 128) ? Wih[j * 128 + k] : Whh[j * 128 + (k - 128)];
    else if (j < 384) return (k < 128) ? Wih[j * 128 + k] : 0.0f;
    else              return (k < 128) ? 0.0f : Whh[(j - 128) * 128 + (k - 128)];
}

// ---------------- prep: message weight in MFMA fragment order ----------------
// Wmf[((c*16 + nt)*64 + lane)*8 + j] ; c 0..13, nt 0..15
__global__ void k_prep_msgfrag(const float* __restrict__ Ws, const float* __restrict__ Wd,
                               const float* __restrict__ bs, const float* __restrict__ bd,
                               unsigned short* __restrict__ Wmf, float* __restrict__ bm) {
    int b = blockIdx.x;              // c*16 + nt
    int c = b >> 4, nt = b & 15;
    int lane = threadIdx.x;
    int col0 = lane & 15, q = lane >> 4;
    int n = nt * 16 + col0;
    float f[8];
#pragma unroll
    for (int j = 0; j < 8; ++j) f[j] = wmsg_val(n, c * 32 + q * 8 + j, Ws, Wd);
    ((bf16x8*)Wmf)[(size_t)b * 64 + lane] = pack8(f);
    if (b == 0)
        for (int i = lane; i < 256; i += 64) bm[i] = (i < 128) ? bs[i] : bd[i - 128];
}

// ---------------- prep: GRU weight in MFMA fragment order ----------------
// Wgf[((c*32 + nt)*64 + lane)*8 + j] ; c 0..7, nt 0..31
__global__ void k_prep_grufrag(const float* __restrict__ Wih, const float* __restrict__ Whh,
                               const float* __restrict__ bih, const float* __restrict__ bhh,
                               unsigned short* __restrict__ Wgf, float* __restrict__ bg) {
    int b = blockIdx.x;              // c*32 + nt
    int c = b >> 5, nt = b & 31;
    int lane = threadIdx.x;
    int col0 = lane & 15, q = lane >> 4;
    int j0 = nt * 16 + col0;
    float f[8];
#pragma unroll
    for (int j = 0; j < 8; ++j) f[j] = wgru_val(j0, c * 32 + q * 8 + j, Wih, Whh);
    ((bf16x8*)Wgf)[(size_t)b * 64 + lane] = pack8(f);
    if (b == 0)
        for (int i = lane; i < 512; i += 64)
            bg[i] = (i < 256) ? (bih[i] + bhh[i]) : ((i < 384) ? bih[i] : bhh[i - 128]);
}

// ---------------- memory fp32 -> bf16 table ----------------
__global__ void k_memconv(const float* __restrict__ in, unsigned short* __restrict__ outp) {
    int gid = blockIdx.x * 256 + threadIdx.x;
    const float4 v = ((const float4*)in)[gid];
    ushort4 o;
    o.x = f2bf(v.x); o.y = f2bf(v.y); o.z = f2bf(v.z); o.w = f2bf(v.w);
    *(ushort4*)(outp + (size_t)gid * 4) = o;
}

// ---------------- per-event: t_rel, counts, timestamp max ----------------
__global__ void k_pre(const int* __restrict__ t, const int* __restrict__ src,
                      const int* __restrict__ dst, const int* __restrict__ lu,
                      float* __restrict__ trel_s, float* __restrict__ trel_d,
                      int* cnt, int* lu_tmp) {
    int e = blockIdx.x * 256 + threadIdx.x;
    int s = src[e], d = dst[e], tv = t[e];
    trel_s[e] = (float)(tv - lu[s]);
    trel_d[e] = (float)(tv - lu[d]);
    atomicAdd(&cnt[s], 1);
    atomicAdd(&cnt[d], 1);
    atomicMax(&lu_tmp[s], tv);
    atomicMax(&lu_tmp[d], tv);
}

// ---------------- CSR scan: 3 stages ----------------
__global__ void k_scan1(const int* __restrict__ cnt, int* __restrict__ bsum) {
    __shared__ int red[256];
    int tid = threadIdx.x;
    red[tid] = cnt[blockIdx.x * 256 + tid];
    __syncthreads();
    for (int s = 128; s > 0; s >>= 1) {
        if (tid < s) red[tid] += red[tid + s];
        __syncthreads();
    }
    if (tid == 0) bsum[blockIdx.x] = red[0];
}
__global__ void k_scan2(const int* __restrict__ bsum, int* __restrict__ boff) {
    __shared__ int sb[512];
    int tid = threadIdx.x;
    int v = bsum[tid];
    sb[tid] = v;
    __syncthreads();
    for (int d = 1; d < 512; d <<= 1) {
        int u = (tid >= d) ? sb[tid - d] : 0;
        __syncthreads();
        sb[tid] += u;
        __syncthreads();
    }
    boff[tid] = sb[tid] - v;   // exclusive
}
__global__ void k_scan3(const int* __restrict__ cnt, const int* __restrict__ boff,
                        int* __restrict__ off, int* __restrict__ cursor) {
    __shared__ int sb[256];
    int tid = threadIdx.x;
    int i = blockIdx.x * 256 + tid;
    int v = cnt[i];
    sb[tid] = v;
    __syncthreads();
    for (int d = 1; d < 256; d <<= 1) {
        int u = (tid >= d) ? sb[tid - d] : 0;
        __syncthreads();
        sb[tid] += u;
        __syncthreads();
    }
    int o = boff[blockIdx.x] + sb[tid] - v;
    off[i] = o;
    cursor[i] = o;
}
// inverse permutation: event-side -> sorted position
__global__ void k_fill(const int* __restrict__ src, const int* __restrict__ dst,
                       int* cursor, int* __restrict__ pos2) {
    int e2 = blockIdx.x * 256 + threadIdx.x;   // [0,2E): <E = s-side, >=E = d-side
    int node = (e2 < EE) ? src[e2] : dst[e2 - EE];
    pos2[e2] = atomicAdd(&cursor[node], 1);
}

// ---------------- message GEMM -> msg_sorted[2E][128] bf16 ----------------
// 64 events x 256 outputs. K=448 in 7 super-chunks of K=64, one barrier each
// (32 MFMAs/wave per barrier interval). 2-deep register prefetch: global loads
// for chunk t+2 issue at the top of chunk t; chunk t+1's registers are written
// to the alternate LDS buffer right after the barrier (T14 async-STAGE split).
// acc[4][4] = 64 acc regs keeps 3 blocks/CU. Epilogue: per-wave LDS transpose
// (reuses As) -> 16B coalesced row stores (WRITE_SIZE = ideal, proven r1).
__launch_bounds__(256, 3)
__global__ void k_msg(const unsigned short* __restrict__ memb,
                      const float* __restrict__ raw,
                      const float* __restrict__ trel_s,
                      const float* __restrict__ trel_d,
                      const unsigned short* __restrict__ Wmf,
                      const float* __restrict__ bm,
                      const int* __restrict__ src, const int* __restrict__ dst,
                      const int* __restrict__ pos2,
                      const float* __restrict__ tw, const float* __restrict__ tb,
                      unsigned short* __restrict__ msg) {
    __shared__ int s_idx[64], d_idx[64], s_pos[64], d_pos[64];
    __shared__ float s_tw[32], s_tb[32];
    __shared__ __align__(16) unsigned short As[2][64 * 72];   // 64 rows x 64 cols, +8 pad

    const int tid = threadIdx.x;
    const int e0 = blockIdx.x * 64;
    if (tid < 64)        { s_idx[tid] = src[e0 + tid];            s_pos[tid] = pos2[e0 + tid]; }
    else if (tid < 128)  { d_idx[tid - 64] = dst[e0 + tid - 64];  d_pos[tid - 64] = pos2[EE + e0 + tid - 64]; }
    else if (tid < 160)  s_tw[tid - 128] = tw[tid - 128];
    else if (tid < 192)  s_tb[tid - 160] = tb[tid - 160];
    __syncthreads();

    const int lane = tid & 63, w = tid >> 6;
    const int col0 = lane & 15, q = lane >> 4;

    // fixed per-thread row/seg decompositions for staging (64 rows x 64 cols)
    const int mrow0 = tid >> 3, mseg = tid & 7;          // memb: 16B items, item1 = row+32
    const int rrow  = tid >> 4, rseg = tid & 15;         // raw: float4 items, +16 rows/iter
    const int trow  = tid >> 2, tq   = tid & 3;          // tenc: 16 cos per thread

    // prefetch registers (explicitly named -> stay in VGPRs, rule #20)
    float4 p0, p1, p2, p3;

    auto stage_load = [&](int t) {
        if (t < 4) {                 // t=0,1: mem_s ; t=2,3: mem_d ; cols (t&1)*64
            int colb = (t & 1) * 64;
            int n0i = (t < 2) ? s_idx[mrow0] : d_idx[mrow0];
            int n1i = (t < 2) ? s_idx[mrow0 + 32] : d_idx[mrow0 + 32];
            p0 = *(const float4*)(memb + (size_t)n0i * 128 + colb + mseg * 8);
            p1 = *(const float4*)(memb + (size_t)n1i * 128 + colb + mseg * 8);
        } else if (t < 6) {          // t=4,5: raw cols (t&1)*64 (fp32)
            const float* rbase = raw + (size_t)e0 * 128 + (t & 1) * 64 + rseg * 4;
            p0 = *(const float4*)(rbase + (size_t)(rrow +  0) * 128);
            p1 = *(const float4*)(rbase + (size_t)(rrow + 16) * 128);
            p2 = *(const float4*)(rbase + (size_t)(rrow + 32) * 128);
            p3 = *(const float4*)(rbase + (size_t)(rrow + 48) * 128);
        } else {                     // t=6: time encodings (load trel only)
            p0.x = (tq < 2) ? trel_s[e0 + trow] : trel_d[e0 + trow];
        }
    };

    auto stage_write = [&](int t, unsigned short* A) {
        if (t < 4) {
            *(bf16x8*)&A[mrow0 * 72 + mseg * 8]        = __builtin_bit_cast(bf16x8, p0);
            *(bf16x8*)&A[(mrow0 + 32) * 72 + mseg * 8] = __builtin_bit_cast(bf16x8, p1);
        } else if (t < 6) {
            ushort4 o;
            o.x = f2bf(p0.x); o.y = f2bf(p0.y); o.z = f2bf(p0.z); o.w = f2bf(p0.w);
            *(ushort4*)&A[(rrow +  0) * 72 + rseg * 4] = o;
            o.x = f2bf(p1.x); o.y = f2bf(p1.y); o.z = f2bf(p1.z); o.w = f2bf(p1.w);
            *(ushort4*)&A[(rrow + 16) * 72 + rseg * 4] = o;
            o.x = f2bf(p2.x); o.y = f2bf(p2.y); o.z = f2bf(p2.z); o.w = f2bf(p2.w);
            *(ushort4*)&A[(rrow + 32) * 72 + rseg * 4] = o;
            o.x = f2bf(p3.x); o.y = f2bf(p3.y); o.z = f2bf(p3.z); o.w = f2bf(p3.w);
            *(ushort4*)&A[(rrow + 48) * 72 + rseg * 4] = o;
        } else {
            // cols 0-31 = cos(trel_s*tw+tb), cols 32-63 = cos(trel_d*tw+tb)
            float f[16];
            float tr = p0.x;
#pragma unroll
            for (int j = 0; j < 16; ++j) {
                int jj = (tq & 1) * 16 + j;
                f[j] = __cosf(tr * s_tw[jj] + s_tb[jj]);
            }
            *(bf16x8*)&A[trow * 72 + tq * 16]     = pack8(&f[0]);
            *(bf16x8*)&A[trow * 72 + tq * 16 + 8] = pack8(&f[8]);
        }
    };

    f32x4 acc[4][4];
#pragma unroll
    for (int a = 0; a < 4; ++a)
#pragma unroll
        for (int b = 0; b < 4; ++b)
#pragma unroll
            for (int i = 0; i < 4; ++i) acc[a][b][i] = 0.0f;

    // prologue: fill LDS[0] with chunk 0, leave chunk 1 in flight in regs
    stage_load(0);
    stage_write(0, As[0]);
    stage_load(1);
    __syncthreads();

#pragma unroll
    for (int t = 0; t < 7; ++t) {
        unsigned short* A = As[t & 1];
        // write chunk t+1 (regs loaded 1 chunk ago) into the alternate buffer
        if (t < 6) stage_write(t + 1, As[(t + 1) & 1]);
        // issue chunk t+2's global loads (full chunk of latency budget)
        if (t < 5) stage_load(t + 2);
#pragma unroll
        for (int kk = 0; kk < 2; ++kk) {
            bf16x8 bfr[4];
            const bf16x8* Wc = (const bf16x8*)Wmf + (size_t)(2 * t + kk) * 16 * 64;
#pragma unroll
            for (int nl = 0; nl < 4; ++nl)
                bfr[nl] = Wc[(w * 4 + nl) * 64 + lane];
            bf16x8 afr[4];
#pragma unroll
            for (int mt = 0; mt < 4; ++mt)
                afr[mt] = *(const bf16x8*)&A[(mt * 16 + col0) * 72 + kk * 32 + q * 8];
#pragma unroll
            for (int mt = 0; mt < 4; ++mt)
#pragma unroll
                for (int nl = 0; nl < 4; ++nl)
                    acc[mt][nl] = __builtin_amdgcn_mfma_f32_16x16x32_bf16(afr[mt], bfr[nl], acc[mt][nl], 0, 0, 0);
        }
        __syncthreads();
    }

    // ---- epilogue: bias+relu, per-wave LDS transpose (reuse As), 16B stores ----
    // per-wave scratch: 16 rows x 80 shorts (160B stride, 16B aligned); row holds
    // 8 granules of 16B, granule-XOR-swizzled by row to break bank aliasing.
    unsigned short* scr = &As[0][0] + w * 1280;
    const bool is_s = (w < 2);
#pragma unroll
    for (int mt = 0; mt < 4; ++mt) {
#pragma unroll
        for (int nl = 0; nl < 4; ++nl) {
            int j = (w * 4 + nl) * 16 + col0;
            float bv = bm[j];
            int gl = nl * 2 + (col0 >> 3);      // logical 16B granule within 64-col tile
            int ci = col0 & 7;                  // short index within granule
#pragma unroll
            for (int r = 0; r < 4; ++r) {
                int rr = q * 4 + r;             // row within 16-row tile
                float v = fmaxf(acc[mt][nl][r] + bv, 0.0f);
                scr[rr * 80 + ((gl + rr) & 7) * 8 + ci] = f2bf(v);
            }
        }
        // wave-local: DS ops are in-order per wave; just wait for writes to land
        asm volatile("s_waitcnt lgkmcnt(0)" ::: "memory");
        {
            int rr2 = lane & 15, p = lane >> 4;
            int ev = mt * 16 + rr2;
            int pos = is_s ? s_pos[ev] : d_pos[ev];
            bf16x8 v0 = *(const bf16x8*)&scr[rr2 * 80 + (((2 * p)     + rr2) & 7) * 8];
            bf16x8 v1 = *(const bf16x8*)&scr[rr2 * 80 + (((2 * p + 1) + rr2) & 7) * 8];
            unsigned short* dstp = msg + (size_t)pos * 128 + (w & 1) * 64 + p * 16;
            *(bf16x8*)dstp = v0;
            *(bf16x8*)(dstp + 8) = v1;
        }
        asm volatile("s_waitcnt lgkmcnt(0)" ::: "memory");
    }
}

// ---------------- fused mean-aggregation (sorted, contiguous) + GRU ----------------
// 32 nodes/block, 256 threads. B frags direct from global; no barriers in K-loop.
__launch_bounds__(256, 3)
__global__ void k_gru(const unsigned short* __restrict__ msg,
                      const int* __restrict__ off, const int* __restrict__ cnt,
                      const float* __restrict__ memory,
                      const unsigned short* __restrict__ Wgf,
                      const float* __restrict__ bg,
                      float* __restrict__ out) {
    __shared__ __align__(16) unsigned short Xs[32 * 264];

    const int tid = threadIdx.x;
    const int n0 = blockIdx.x * 32;

    // aggregation: 8 threads/node, 16 feats each; msg rows contiguous per node
    {
        int g = tid >> 3, sub = tid & 7;
        int node = n0 + g;
        int beg = off[node], cn = cnt[node];
        float a[16];
#pragma unroll
        for (int i = 0; i < 16; ++i) a[i] = 0.0f;
        for (int m = 0; m < cn; ++m) {
            const bf16x8* p = (const bf16x8*)(msg + (size_t)(beg + m) * 128 + sub * 16);
            bf16x8 v0 = p[0], v1 = p[1];
#pragma unroll
            for (int k = 0; k < 8; ++k) {
                a[k]     += bf2f((unsigned short)v0[k]);
                a[8 + k] += bf2f((unsigned short)v1[k]);
            }
        }
        float inv = 1.0f / (float)(cn > 1 ? cn : 1);
#pragma unroll
        for (int i = 0; i < 16; ++i) a[i] *= inv;
        *(bf16x8*)&Xs[g * 264 + sub * 16] = pack8(&a[0]);
        *(bf16x8*)&Xs[g * 264 + sub * 16 + 8] = pack8(&a[8]);
        // memory half
        float f[16];
        const float4* mp = (const float4*)(memory + (size_t)node * 128 + sub * 16);
#pragma unroll
        for (int s = 0; s < 4; ++s) {
            float4 v = mp[s];
            f[s * 4 + 0] = v.x; f[s * 4 + 1] = v.y; f[s * 4 + 2] = v.z; f[s * 4 + 3] = v.w;
        }
        *(bf16x8*)&Xs[g * 264 + 128 + sub * 16] = pack8(&f[0]);
        *(bf16x8*)&Xs[g * 264 + 128 + sub * 16 + 8] = pack8(&f[8]);
    }
    __syncthreads();

    const int lane = tid & 63, w = tid >> 6;
    const int col0 = lane & 15, q = lane >> 4;

    f32x4 acc[2][4][2];   // [mt][gate][fh]
#pragma unroll
    for (int a = 0; a < 2; ++a)
#pragma unroll
        for (int g = 0; g < 4; ++g)
#pragma unroll
            for (int f = 0; f < 2; ++f)
#pragma unroll
                for (int i = 0; i < 4; ++i) acc[a][g][f][i] = 0.0f;

#pragma unroll
    for (int c = 0; c < 8; ++c) {
        bf16x8 bfr[4][2];
        const bf16x8* Wc = (const bf16x8*)Wgf + (size_t)c * 32 * 64;
#pragma unroll
        for (int g = 0; g < 4; ++g)
#pragma unroll
            for (int fh = 0; fh < 2; ++fh)
                bfr[g][fh] = Wc[(8 * g + 2 * w + fh) * 64 + lane];
        bf16x8 afr[2];
#pragma unroll
        for (int mt = 0; mt < 2; ++mt)
            afr[mt] = *(const bf16x8*)&Xs[(mt * 16 + col0) * 264 + c * 32 + q * 8];
#pragma unroll
        for (int mt = 0; mt < 2; ++mt)
#pragma unroll
            for (int g = 0; g < 4; ++g)
#pragma unroll
                for (int fh = 0; fh < 2; ++fh)
                    acc[mt][g][fh] = __builtin_amdgcn_mfma_f32_16x16x32_bf16(afr[mt], bfr[g][fh], acc[mt][g][fh], 0, 0, 0);
    }

    // epilogue: gates + blend
#pragma unroll
    for (int fh = 0; fh < 2; ++fh) {
        int feat = w * 32 + fh * 16 + col0;
        float b_r = bg[feat], b_z = bg[128 + feat], b_in = bg[256 + feat], b_hn = bg[384 + feat];
#pragma unroll
        for (int mt = 0; mt < 2; ++mt) {
#pragma unroll
            for (int r = 0; r < 4; ++r) {
                int node = n0 + mt * 16 + q * 4 + r;
                float rr = sigmoidf_(acc[mt][0][fh][r] + b_r);
                float zz = sigmoidf_(acc[mt][1][fh][r] + b_z);
                float nn = tanhf_((acc[mt][2][fh][r] + b_in) + rr * (acc[mt][3][fh][r] + b_hn));
                float h = memory[(size_t)node * 128 + feat];
                out[(size_t)node * 128 + feat] = (1.0f - zz) * nn + zz * h;
            }
        }
    }
}

// ---------------- last_update -> float output ----------------
__global__ void k_lu(const int* __restrict__ lu_tmp, float* __restrict__ outp) {
    int i = blockIdx.x * 256 + threadIdx.x;
    outp[i] = (float)lu_tmp[i];
}

extern "C" void kernel_launch(void* const* d_in, const int* in_sizes, int n_in,
                              void* d_out, int out_size, void* d_ws, size_t ws_size,
                              hipStream_t stream) {
    const float* memory = (const float*)d_in[0];
    const float* raw    = (const float*)d_in[1];
    const float* tw     = (const float*)d_in[2];
    const float* tb     = (const float*)d_in[3];
    const float* Wms    = (const float*)d_in[4];
    const float* bms    = (const float*)d_in[5];
    const float* Wmd    = (const float*)d_in[6];
    const float* bmd    = (const float*)d_in[7];
    const float* Wih    = (const float*)d_in[8];
    const float* Whh    = (const float*)d_in[9];
    const float* bih    = (const float*)d_in[10];
    const float* bhh    = (const float*)d_in[11];
    const int* src = (const int*)d_in[12];
    const int* dst = (const int*)d_in[13];
    const int* t   = (const int*)d_in[14];
    const int* lu  = (const int*)d_in[15];

    char* ws = (char*)d_ws;
    size_t ob = 0;
    unsigned short* memb = (unsigned short*)(ws + ob); ob += (size_t)NN * 128 * 2;       // 32 MB
    unsigned short* msg  = (unsigned short*)(ws + ob); ob += (size_t)2 * EE * 128 * 2;   // 128 MB (sorted)
    float* trel_s        = (float*)(ws + ob);          ob += (size_t)EE * 4;
    float* trel_d        = (float*)(ws + ob);          ob += (size_t)EE * 4;
    int* cnt             = (int*)(ws + ob);            ob += (size_t)NN * 4;
    int* off             = (int*)(ws + ob);            ob += (size_t)NN * 4;
    int* cursor          = (int*)(ws + ob);            ob += (size_t)NN * 4;
    int* lu_tmp          = (int*)(ws + ob);            ob += (size_t)NN * 4;
    int* pos2            = (int*)(ws + ob);            ob += (size_t)2 * EE * 4;         // 2 MB
    int* bsum            = (int*)(ws + ob);            ob += 512 * 4;
    int* boff            = (int*)(ws + ob);            ob += 512 * 4;
    unsigned short* Wmf  = (unsigned short*)(ws + ob); ob += (size_t)14 * 16 * 64 * 8 * 2;
    float* bm            = (float*)(ws + ob);          ob += 256 * 4;
    unsigned short* Wgf  = (unsigned short*)(ws + ob); ob += (size_t)8 * 32 * 64 * 8 * 2;
    float* bg            = (float*)(ws + ob);          ob += 512 * 4;

    float* out = (float*)d_out;

    hipMemsetAsync(cnt, 0, (size_t)NN * 4, stream);
    hipMemsetAsync(lu_tmp, 0, (size_t)NN * 4, stream);

    k_prep_msgfrag<<<14 * 16, 64, 0, stream>>>(Wms, Wmd, bms, bmd, Wmf, bm);
    k_prep_grufrag<<<8 * 32, 64, 0, stream>>>(Wih, Whh, bih, bhh, Wgf, bg);
    k_memconv<<<(NN * 128 / 4) / 256, 256, 0, stream>>>(memory, memb);
    k_pre<<<EE / 256, 256, 0, stream>>>(t, src, dst, lu, trel_s, trel_d, cnt, lu_tmp);
    k_scan1<<<512, 256, 0, stream>>>(cnt, bsum);
    k_scan2<<<1, 512, 0, stream>>>(bsum, boff);
    k_scan3<<<512, 256, 0, stream>>>(cnt, boff, off, cursor);
    k_fill<<<2 * EE / 256, 256, 0, stream>>>(src, dst, cursor, pos2);
    k_msg<<<EE / 64, 256, 0, stream>>>(memb, raw, trel_s, trel_d, Wmf, bm, src, dst, pos2, tw, tb, msg);
    k_gru<<<NN / 32, 256, 0, stream>>>(msg, off, cnt, memory, Wgf, bg, out);
    k_lu<<<NN / 256, 256, 0, stream>>>(lu_tmp, out + (size_t)NN * 128);
}

// Round 3
// 552.249 us; speedup vs baseline: 1.0665x; 1.0260x over previous
//
#include <hip/hip_runtime.h>
#include <cstdint>
#include <cstddef>

// Problem dims (fixed)
#define NN 131072      // nodes
#define EE 262144      // events
// msg GEMM: K = 448 = [mem_s 128 | mem_d 128 | raw 128 | tenc_s 32 | tenc_d 32], Nout = 256
// gru GEMM: K = 256 = [aggr 128 | memory 128], Nout = 512 = [r | z | i_n | h_n]

typedef __attribute__((ext_vector_type(8))) short bf16x8;
typedef __attribute__((ext_vector_type(4))) float f32x4;

__device__ __forceinline__ unsigned short f2bf(float f) {
    unsigned int u = __builtin_bit_cast(unsigned int, f);
    u += 0x7FFFu + ((u >> 16) & 1u);   // RNE
    return (unsigned short)(u >> 16);
}
__device__ __forceinline__ float bf2f(unsigned short s) {
    unsigned int u = ((unsigned int)s) << 16;
    return __builtin_bit_cast(float, u);
}
__device__ __forceinline__ float sigmoidf_(float x) { return 1.0f / (1.0f + __expf(-x)); }
__device__ __forceinline__ float tanhf_(float x) {
    float ax = fabsf(x);
    float e = __expf(-2.0f * ax);
    return copysignf((1.0f - e) / (1.0f + e), x);
}
__device__ __forceinline__ bf16x8 pack8(const float* f) {
    bf16x8 o;
#pragma unroll
    for (int i = 0; i < 8; ++i) o[i] = (short)f2bf(f[i]);
    return o;
}

// logical W' for the fused message GEMM (256 out x 448 in)
__device__ __forceinline__ float wmsg_val(int n, int k, const float* Ws, const float* Wd) {
    if (n < 128) {
        return (k < 416) ? Ws[n * 416 + k] : 0.0f;           // [mem_s, mem_d, raw, tenc_s]
    } else {
        int m = n - 128;
        if (k < 128)       return Wd[m * 416 + 128 + k];     // X' mem_s <- Wd block 1
        else if (k < 256)  return Wd[m * 416 + (k - 128)];   // X' mem_d <- Wd block 0
        else if (k < 384)  return Wd[m * 416 + k];           // raw
        else if (k < 416)  return 0.0f;                      // tenc_s unused by msg_d
        else               return Wd[m * 416 + 384 + (k - 416)]; // tenc_d
    }
}
// logical W for the GRU GEMM (512 out x 256 in)
__device__ __forceinline__ float wgru_val(int j, int k, const float* Wih, const float* Whh) {
    if (j < 256)      return (k < 128) ? Wih[j * 128 + k] : Whh[j * 128 + (k - 128)];
    else if (j < 384) return (k < 128) ? Wih[j * 128 + k] : 0.0f;
    else              return (k < 128) ? 0.0f : Whh[(j - 128) * 128 + (k - 128)];
}

// ---------------- prep: message weight in MFMA fragment order ----------------
// Wmf[((c*16 + nt)*64 + lane)*8 + j] ; c 0..13, nt 0..15
__global__ void k_prep_msgfrag(const float* __restrict__ Ws, const float* __restrict__ Wd,
                               const float* __restrict__ bs, const float* __restrict__ bd,
                               unsigned short* __restrict__ Wmf, float* __restrict__ bm) {
    int b = blockIdx.x;              // c*16 + nt
    int c = b >> 4, nt = b & 15;
    int lane = threadIdx.x;
    int col0 = lane & 15, q = lane >> 4;
    int n = nt * 16 + col0;
    float f[8];
#pragma unroll
    for (int j = 0; j < 8; ++j) f[j] = wmsg_val(n, c * 32 + q * 8 + j, Ws, Wd);
    ((bf16x8*)Wmf)[(size_t)b * 64 + lane] = pack8(f);
    if (b == 0)
        for (int i = lane; i < 256; i += 64) bm[i] = (i < 128) ? bs[i] : bd[i - 128];
}

// ---------------- prep: GRU weight in MFMA fragment order ----------------
// Wgf[((c*32 + nt)*64 + lane)*8 + j] ; c 0..7, nt 0..31
__global__ void k_prep_grufrag(const float* __restrict__ Wih, const float* __restrict__ Whh,
                               const float* __restrict__ bih, const float* __restrict__ bhh,
                               unsigned short* __restrict__ Wgf, float* __restrict__ bg) {
    int b = blockIdx.x;              // c*32 + nt
    int c = b >> 5, nt = b & 31;
    int lane = threadIdx.x;
    int col0 = lane & 15, q = lane >> 4;
    int j0 = nt * 16 + col0;
    float f[8];
#pragma unroll
    for (int j = 0; j < 8; ++j) f[j] = wgru_val(j0, c * 32 + q * 8 + j, Wih, Whh);
    ((bf16x8*)Wgf)[(size_t)b * 64 + lane] = pack8(f);
    if (b == 0)
        for (int i = lane; i < 512; i += 64)
            bg[i] = (i < 256) ? (bih[i] + bhh[i]) : ((i < 384) ? bih[i] : bhh[i - 128]);
}

// ---------------- memory fp32 -> bf16 table ----------------
__global__ void k_memconv(const float* __restrict__ in, unsigned short* __restrict__ outp) {
    int gid = blockIdx.x * 256 + threadIdx.x;
    const float4 v = ((const float4*)in)[gid];
    ushort4 o;
    o.x = f2bf(v.x); o.y = f2bf(v.y); o.z = f2bf(v.z); o.w = f2bf(v.w);
    *(ushort4*)(outp + (size_t)gid * 4) = o;
}

// ---------------- per-event: t_rel, counts, timestamp max ----------------
__global__ void k_pre(const int* __restrict__ t, const int* __restrict__ src,
                      const int* __restrict__ dst, const int* __restrict__ lu,
                      float* __restrict__ trel_s, float* __restrict__ trel_d,
                      int* cnt, int* lu_tmp) {
    int e = blockIdx.x * 256 + threadIdx.x;
    int s = src[e], d = dst[e], tv = t[e];
    trel_s[e] = (float)(tv - lu[s]);
    trel_d[e] = (float)(tv - lu[d]);
    atomicAdd(&cnt[s], 1);
    atomicAdd(&cnt[d], 1);
    atomicMax(&lu_tmp[s], tv);
    atomicMax(&lu_tmp[d], tv);
}

// ---------------- CSR scan: 3 stages ----------------
__global__ void k_scan1(const int* __restrict__ cnt, int* __restrict__ bsum) {
    __shared__ int red[256];
    int tid = threadIdx.x;
    red[tid] = cnt[blockIdx.x * 256 + tid];
    __syncthreads();
    for (int s = 128; s > 0; s >>= 1) {
        if (tid < s) red[tid] += red[tid + s];
        __syncthreads();
    }
    if (tid == 0) bsum[blockIdx.x] = red[0];
}
__global__ void k_scan2(const int* __restrict__ bsum, int* __restrict__ boff) {
    __shared__ int sb[512];
    int tid = threadIdx.x;
    int v = bsum[tid];
    sb[tid] = v;
    __syncthreads();
    for (int d = 1; d < 512; d <<= 1) {
        int u = (tid >= d) ? sb[tid - d] : 0;
        __syncthreads();
        sb[tid] += u;
        __syncthreads();
    }
    boff[tid] = sb[tid] - v;   // exclusive
}
__global__ void k_scan3(const int* __restrict__ cnt, const int* __restrict__ boff,
                        int* __restrict__ off, int* __restrict__ cursor) {
    __shared__ int sb[256];
    int tid = threadIdx.x;
    int i = blockIdx.x * 256 + tid;
    int v = cnt[i];
    sb[tid] = v;
    __syncthreads();
    for (int d = 1; d < 256; d <<= 1) {
        int u = (tid >= d) ? sb[tid - d] : 0;
        __syncthreads();
        sb[tid] += u;
        __syncthreads();
    }
    int o = boff[blockIdx.x] + sb[tid] - v;
    off[i] = o;
    cursor[i] = o;
}
// inverse permutation: event-side -> sorted position
__global__ void k_fill(const int* __restrict__ src, const int* __restrict__ dst,
                       int* cursor, int* __restrict__ pos2) {
    int e2 = blockIdx.x * 256 + threadIdx.x;   // [0,2E): <E = s-side, >=E = d-side
    int node = (e2 < EE) ? src[e2] : dst[e2 - EE];
    pos2[e2] = atomicAdd(&cursor[node], 1);
}

// ---------------- message GEMM -> msg_sorted[2E][128] bf16 ----------------
// 64 events x 256 outputs. K=448 in 7 super-chunks of K=64, one barrier each
// (32 MFMAs/wave per barrier interval). 2-deep register prefetch: global loads
// for chunk t+2 issue at the top of chunk t; chunk t+1's registers are written
// to the alternate LDS buffer right after the barrier (T14 async-STAGE split).
// acc[4][4] = 64 acc regs keeps 3 blocks/CU. Epilogue: per-wave LDS transpose
// (reuses As) -> 16B coalesced row stores (WRITE_SIZE = ideal, proven r1).
__launch_bounds__(256, 3)
__global__ void k_msg(const unsigned short* __restrict__ memb,
                      const float* __restrict__ raw,
                      const float* __restrict__ trel_s,
                      const float* __restrict__ trel_d,
                      const unsigned short* __restrict__ Wmf,
                      const float* __restrict__ bm,
                      const int* __restrict__ src, const int* __restrict__ dst,
                      const int* __restrict__ pos2,
                      const float* __restrict__ tw, const float* __restrict__ tb,
                      unsigned short* __restrict__ msg) {
    __shared__ int s_idx[64], d_idx[64], s_pos[64], d_pos[64];
    __shared__ float s_tw[32], s_tb[32];
    __shared__ __align__(16) unsigned short As[2][64 * 72];   // 64 rows x 64 cols, +8 pad

    const int tid = threadIdx.x;
    const int e0 = blockIdx.x * 64;
    if (tid < 64)        { s_idx[tid] = src[e0 + tid];            s_pos[tid] = pos2[e0 + tid]; }
    else if (tid < 128)  { d_idx[tid - 64] = dst[e0 + tid - 64];  d_pos[tid - 64] = pos2[EE + e0 + tid - 64]; }
    else if (tid < 160)  s_tw[tid - 128] = tw[tid - 128];
    else if (tid < 192)  s_tb[tid - 160] = tb[tid - 160];
    __syncthreads();

    const int lane = tid & 63, w = tid >> 6;
    const int col0 = lane & 15, q = lane >> 4;

    // fixed per-thread row/seg decompositions for staging (64 rows x 64 cols)
    const int mrow0 = tid >> 3, mseg = tid & 7;          // memb: 16B items, item1 = row+32
    const int rrow  = tid >> 4, rseg = tid & 15;         // raw: float4 items, +16 rows/iter
    const int trow  = tid >> 2, tq   = tid & 3;          // tenc: 16 cos per thread

    // prefetch registers (explicitly named -> stay in VGPRs, rule #20)
    float4 p0, p1, p2, p3;

    auto stage_load = [&](int t) {
        if (t < 4) {                 // t=0,1: mem_s ; t=2,3: mem_d ; cols (t&1)*64
            int colb = (t & 1) * 64;
            int n0i = (t < 2) ? s_idx[mrow0] : d_idx[mrow0];
            int n1i = (t < 2) ? s_idx[mrow0 + 32] : d_idx[mrow0 + 32];
            p0 = *(const float4*)(memb + (size_t)n0i * 128 + colb + mseg * 8);
            p1 = *(const float4*)(memb + (size_t)n1i * 128 + colb + mseg * 8);
        } else if (t < 6) {          // t=4,5: raw cols (t&1)*64 (fp32)
            const float* rbase = raw + (size_t)e0 * 128 + (t & 1) * 64 + rseg * 4;
            p0 = *(const float4*)(rbase + (size_t)(rrow +  0) * 128);
            p1 = *(const float4*)(rbase + (size_t)(rrow + 16) * 128);
            p2 = *(const float4*)(rbase + (size_t)(rrow + 32) * 128);
            p3 = *(const float4*)(rbase + (size_t)(rrow + 48) * 128);
        } else {                     // t=6: time encodings (load trel only)
            p0.x = (tq < 2) ? trel_s[e0 + trow] : trel_d[e0 + trow];
        }
    };

    auto stage_write = [&](int t, unsigned short* A) {
        if (t < 4) {
            *(bf16x8*)&A[mrow0 * 72 + mseg * 8]        = __builtin_bit_cast(bf16x8, p0);
            *(bf16x8*)&A[(mrow0 + 32) * 72 + mseg * 8] = __builtin_bit_cast(bf16x8, p1);
        } else if (t < 6) {
            ushort4 o;
            o.x = f2bf(p0.x); o.y = f2bf(p0.y); o.z = f2bf(p0.z); o.w = f2bf(p0.w);
            *(ushort4*)&A[(rrow +  0) * 72 + rseg * 4] = o;
            o.x = f2bf(p1.x); o.y = f2bf(p1.y); o.z = f2bf(p1.z); o.w = f2bf(p1.w);
            *(ushort4*)&A[(rrow + 16) * 72 + rseg * 4] = o;
            o.x = f2bf(p2.x); o.y = f2bf(p2.y); o.z = f2bf(p2.z); o.w = f2bf(p2.w);
            *(ushort4*)&A[(rrow + 32) * 72 + rseg * 4] = o;
            o.x = f2bf(p3.x); o.y = f2bf(p3.y); o.z = f2bf(p3.z); o.w = f2bf(p3.w);
            *(ushort4*)&A[(rrow + 48) * 72 + rseg * 4] = o;
        } else {
            // cols 0-31 = cos(trel_s*tw+tb), cols 32-63 = cos(trel_d*tw+tb)
            float f[16];
            float tr = p0.x;
#pragma unroll
            for (int j = 0; j < 16; ++j) {
                int jj = (tq & 1) * 16 + j;
                f[j] = __cosf(tr * s_tw[jj] + s_tb[jj]);
            }
            *(bf16x8*)&A[trow * 72 + tq * 16]     = pack8(&f[0]);
            *(bf16x8*)&A[trow * 72 + tq * 16 + 8] = pack8(&f[8]);
        }
    };

    f32x4 acc[4][4];
#pragma unroll
    for (int a = 0; a < 4; ++a)
#pragma unroll
        for (int b = 0; b < 4; ++b)
#pragma unroll
            for (int i = 0; i < 4; ++i) acc[a][b][i] = 0.0f;

    // prologue: fill LDS[0] with chunk 0, leave chunk 1 in flight in regs
    stage_load(0);
    stage_write(0, As[0]);
    stage_load(1);
    __syncthreads();

#pragma unroll
    for (int t = 0; t < 7; ++t) {
        unsigned short* A = As[t & 1];
        // write chunk t+1 (regs loaded 1 chunk ago) into the alternate buffer
        if (t < 6) stage_write(t + 1, As[(t + 1) & 1]);
        // issue chunk t+2's global loads (full chunk of latency budget)
        if (t < 5) stage_load(t + 2);
#pragma unroll
        for (int kk = 0; kk < 2; ++kk) {
            bf16x8 bfr[4];
            const bf16x8* Wc = (const bf16x8*)Wmf + (size_t)(2 * t + kk) * 16 * 64;
#pragma unroll
            for (int nl = 0; nl < 4; ++nl)
                bfr[nl] = Wc[(w * 4 + nl) * 64 + lane];
            bf16x8 afr[4];
#pragma unroll
            for (int mt = 0; mt < 4; ++mt)
                afr[mt] = *(const bf16x8*)&A[(mt * 16 + col0) * 72 + kk * 32 + q * 8];
#pragma unroll
            for (int mt = 0; mt < 4; ++mt)
#pragma unroll
                for (int nl = 0; nl < 4; ++nl)
                    acc[mt][nl] = __builtin_amdgcn_mfma_f32_16x16x32_bf16(afr[mt], bfr[nl], acc[mt][nl], 0, 0, 0);
        }
        __syncthreads();
    }

    // ---- epilogue: bias+relu, per-wave LDS transpose (reuse As), 16B stores ----
    // per-wave scratch: 16 rows x 80 shorts (160B stride, 16B aligned); row holds
    // 8 granules of 16B, granule-XOR-swizzled by row to break bank aliasing.
    unsigned short* scr = &As[0][0] + w * 1280;
    const bool is_s = (w < 2);
#pragma unroll
    for (int mt = 0; mt < 4; ++mt) {
#pragma unroll
        for (int nl = 0; nl < 4; ++nl) {
            int j = (w * 4 + nl) * 16 + col0;
            float bv = bm[j];
            int gl = nl * 2 + (col0 >> 3);      // logical 16B granule within 64-col tile
            int ci = col0 & 7;                  // short index within granule
#pragma unroll
            for (int r = 0; r < 4; ++r) {
                int rr = q * 4 + r;             // row within 16-row tile
                float v = fmaxf(acc[mt][nl][r] + bv, 0.0f);
                scr[rr * 80 + ((gl + rr) & 7) * 8 + ci] = f2bf(v);
            }
        }
        // wave-local: DS ops are in-order per wave; just wait for writes to land
        asm volatile("s_waitcnt lgkmcnt(0)" ::: "memory");
        {
            int rr2 = lane & 15, p = lane >> 4;
            int ev = mt * 16 + rr2;
            int pos = is_s ? s_pos[ev] : d_pos[ev];
            bf16x8 v0 = *(const bf16x8*)&scr[rr2 * 80 + (((2 * p)     + rr2) & 7) * 8];
            bf16x8 v1 = *(const bf16x8*)&scr[rr2 * 80 + (((2 * p + 1) + rr2) & 7) * 8];
            unsigned short* dstp = msg + (size_t)pos * 128 + (w & 1) * 64 + p * 16;
            *(bf16x8*)dstp = v0;
            *(bf16x8*)(dstp + 8) = v1;
        }
        asm volatile("s_waitcnt lgkmcnt(0)" ::: "memory");
    }
}

// ---------------- fused mean-aggregation (sorted, contiguous) + GRU ----------------
// 64 nodes/block, 256 threads. Each per-chunk B-frag register set is reused by
// 4 m-tiles (was 2): halves the grid-wide Wgf L2 traffic (1 GB -> 512 MB) and
// doubles MFMA work per weight load. acc[4][4][2] = 128 acc regs -> (256,2).
__launch_bounds__(256, 2)
__global__ void k_gru(const unsigned short* __restrict__ msg,
                      const int* __restrict__ off, const int* __restrict__ cnt,
                      const float* __restrict__ memory,
                      const unsigned short* __restrict__ Wgf,
                      const float* __restrict__ bg,
                      float* __restrict__ out) {
    __shared__ __align__(16) unsigned short Xs[64 * 264];

    const int tid = threadIdx.x;
    const int n0 = blockIdx.x * 64;

    // aggregation: 8 threads/node, 16 feats each; two 32-node passes
#pragma unroll
    for (int h = 0; h < 2; ++h) {
        int g = tid >> 3, sub = tid & 7;
        int gr = h * 32 + g;
        int node = n0 + gr;
        int beg = off[node], cn = cnt[node];
        float a[16];
#pragma unroll
        for (int i = 0; i < 16; ++i) a[i] = 0.0f;
        for (int m = 0; m < cn; ++m) {
            const bf16x8* p = (const bf16x8*)(msg + (size_t)(beg + m) * 128 + sub * 16);
            bf16x8 v0 = p[0], v1 = p[1];
#pragma unroll
            for (int k = 0; k < 8; ++k) {
                a[k]     += bf2f((unsigned short)v0[k]);
                a[8 + k] += bf2f((unsigned short)v1[k]);
            }
        }
        float inv = 1.0f / (float)(cn > 1 ? cn : 1);
#pragma unroll
        for (int i = 0; i < 16; ++i) a[i] *= inv;
        *(bf16x8*)&Xs[gr * 264 + sub * 16] = pack8(&a[0]);
        *(bf16x8*)&Xs[gr * 264 + sub * 16 + 8] = pack8(&a[8]);
        // memory half
        float f[16];
        const float4* mp = (const float4*)(memory + (size_t)node * 128 + sub * 16);
#pragma unroll
        for (int s = 0; s < 4; ++s) {
            float4 v = mp[s];
            f[s * 4 + 0] = v.x; f[s * 4 + 1] = v.y; f[s * 4 + 2] = v.z; f[s * 4 + 3] = v.w;
        }
        *(bf16x8*)&Xs[gr * 264 + 128 + sub * 16] = pack8(&f[0]);
        *(bf16x8*)&Xs[gr * 264 + 128 + sub * 16 + 8] = pack8(&f[8]);
    }
    __syncthreads();

    const int lane = tid & 63, w = tid >> 6;
    const int col0 = lane & 15, q = lane >> 4;

    f32x4 acc[4][4][2];   // [mt][gate][fh]
#pragma unroll
    for (int a = 0; a < 4; ++a)
#pragma unroll
        for (int g = 0; g < 4; ++g)
#pragma unroll
            for (int f = 0; f < 2; ++f)
#pragma unroll
                for (int i = 0; i < 4; ++i) acc[a][g][f][i] = 0.0f;

#pragma unroll
    for (int c = 0; c < 8; ++c) {
        bf16x8 bfr[4][2];
        const bf16x8* Wc = (const bf16x8*)Wgf + (size_t)c * 32 * 64;
#pragma unroll
        for (int g = 0; g < 4; ++g)
#pragma unroll
            for (int fh = 0; fh < 2; ++fh)
                bfr[g][fh] = Wc[(8 * g + 2 * w + fh) * 64 + lane];
        bf16x8 afr[4];
#pragma unroll
        for (int mt = 0; mt < 4; ++mt)
            afr[mt] = *(const bf16x8*)&Xs[(mt * 16 + col0) * 264 + c * 32 + q * 8];
#pragma unroll
        for (int mt = 0; mt < 4; ++mt)
#pragma unroll
            for (int g = 0; g < 4; ++g)
#pragma unroll
                for (int fh = 0; fh < 2; ++fh)
                    acc[mt][g][fh] = __builtin_amdgcn_mfma_f32_16x16x32_bf16(afr[mt], bfr[g][fh], acc[mt][g][fh], 0, 0, 0);
    }

    // epilogue: gates + blend
#pragma unroll
    for (int fh = 0; fh < 2; ++fh) {
        int feat = w * 32 + fh * 16 + col0;
        float b_r = bg[feat], b_z = bg[128 + feat], b_in = bg[256 + feat], b_hn = bg[384 + feat];
#pragma unroll
        for (int mt = 0; mt < 4; ++mt) {
#pragma unroll
            for (int r = 0; r < 4; ++r) {
                int node = n0 + mt * 16 + q * 4 + r;
                float rr = sigmoidf_(acc[mt][0][fh][r] + b_r);
                float zz = sigmoidf_(acc[mt][1][fh][r] + b_z);
                float nn = tanhf_((acc[mt][2][fh][r] + b_in) + rr * (acc[mt][3][fh][r] + b_hn));
                float h = memory[(size_t)node * 128 + feat];
                out[(size_t)node * 128 + feat] = (1.0f - zz) * nn + zz * h;
            }
        }
    }
}

// ---------------- last_update -> float output ----------------
__global__ void k_lu(const int* __restrict__ lu_tmp, float* __restrict__ outp) {
    int i = blockIdx.x * 256 + threadIdx.x;
    outp[i] = (float)lu_tmp[i];
}

extern "C" void kernel_launch(void* const* d_in, const int* in_sizes, int n_in,
                              void* d_out, int out_size, void* d_ws, size_t ws_size,
                              hipStream_t stream) {
    const float* memory = (const float*)d_in[0];
    const float* raw    = (const float*)d_in[1];
    const float* tw     = (const float*)d_in[2];
    const float* tb     = (const float*)d_in[3];
    const float* Wms    = (const float*)d_in[4];
    const float* bms    = (const float*)d_in[5];
    const float* Wmd    = (const float*)d_in[6];
    const float* bmd    = (const float*)d_in[7];
    const float* Wih    = (const float*)d_in[8];
    const float* Whh    = (const float*)d_in[9];
    const float* bih    = (const float*)d_in[10];
    const float* bhh    = (const float*)d_in[11];
    const int* src = (const int*)d_in[12];
    const int* dst = (const int*)d_in[13];
    const int* t   = (const int*)d_in[14];
    const int* lu  = (const int*)d_in[15];

    char* ws = (char*)d_ws;
    size_t ob = 0;
    unsigned short* memb = (unsigned short*)(ws + ob); ob += (size_t)NN * 128 * 2;       // 32 MB
    unsigned short* msg  = (unsigned short*)(ws + ob); ob += (size_t)2 * EE * 128 * 2;   // 128 MB (sorted)
    float* trel_s        = (float*)(ws + ob);          ob += (size_t)EE * 4;
    float* trel_d        = (float*)(ws + ob);          ob += (size_t)EE * 4;
    int* cnt             = (int*)(ws + ob);            ob += (size_t)NN * 4;
    int* off             = (int*)(ws + ob);            ob += (size_t)NN * 4;
    int* cursor          = (int*)(ws + ob);            ob += (size_t)NN * 4;
    int* lu_tmp          = (int*)(ws + ob);            ob += (size_t)NN * 4;
    int* pos2            = (int*)(ws + ob);            ob += (size_t)2 * EE * 4;         // 2 MB
    int* bsum            = (int*)(ws + ob);            ob += 512 * 4;
    int* boff            = (int*)(ws + ob);            ob += 512 * 4;
    unsigned short* Wmf  = (unsigned short*)(ws + ob); ob += (size_t)14 * 16 * 64 * 8 * 2;
    float* bm            = (float*)(ws + ob);          ob += 256 * 4;
    unsigned short* Wgf  = (unsigned short*)(ws + ob); ob += (size_t)8 * 32 * 64 * 8 * 2;
    float* bg            = (float*)(ws + ob);          ob += 512 * 4;

    float* out = (float*)d_out;

    hipMemsetAsync(cnt, 0, (size_t)NN * 4, stream);
    hipMemsetAsync(lu_tmp, 0, (size_t)NN * 4, stream);

    k_prep_msgfrag<<<14 * 16, 64, 0, stream>>>(Wms, Wmd, bms, bmd, Wmf, bm);
    k_prep_grufrag<<<8 * 32, 64, 0, stream>>>(Wih, Whh, bih, bhh, Wgf, bg);
    k_memconv<<<(NN * 128 / 4) / 256, 256, 0, stream>>>(memory, memb);
    k_pre<<<EE / 256, 256, 0, stream>>>(t, src, dst, lu, trel_s, trel_d, cnt, lu_tmp);
    k_scan1<<<512, 256, 0, stream>>>(cnt, bsum);
    k_scan2<<<1, 512, 0, stream>>>(bsum, boff);
    k_scan3<<<512, 256, 0, stream>>>(cnt, boff, off, cursor);
    k_fill<<<2 * EE / 256, 256, 0, stream>>>(src, dst, cursor, pos2);
    k_msg<<<EE / 64, 256, 0, stream>>>(memb, raw, trel_s, trel_d, Wmf, bm, src, dst, pos2, tw, tb, msg);
    k_gru<<<NN / 64, 256, 0, stream>>>(msg, off, cnt, memory, Wgf, bg, out);
    k_lu<<<NN / 256, 256, 0, stream>>>(lu_tmp, out + (size_t)NN * 128);
}